// Round 1
// baseline (72.895 us; speedup 1.0000x reference)
//
#include <hip/hip_runtime.h>

#define NB    2
#define NCAM  6
#define CFEAT 80
#define FH    32
#define FW    88
#define NPTS  150000
#define BEVN  180
#define NCELL (BEVN*BEVN)

// ---- ws layout ----
// doubles at byte offset 0:
//   invLam : NB*9            (inverse of lidar_aug 3x3, f64)
//   lamT   : NB*3            (lidar_aug translation)
//   invM   : NB*NCAM*9       (inverse of buggy-scaled lidar2image 3x3)
//   tScl   : NB*NCAM*3       (buggy-scaled translation)
// int32 at byte offset 4096:
//   win    : NB*NCAM*NCELL   (packed winner per BEV cell, -1 = none)
#define OFF_INVLAM 0
#define OFF_LAMT   (OFF_INVLAM + NB*9)
#define OFF_INVM   (OFF_LAMT + NB*3)
#define OFF_TSCL   (OFF_INVM + NB*NCAM*9)
#define WIN_BYTE_OFF 4096

__device__ inline void inv3x3(const double m[9], double* o) {
    double c00 = m[4]*m[8] - m[5]*m[7];
    double c01 = m[5]*m[6] - m[3]*m[8];
    double c02 = m[3]*m[7] - m[4]*m[6];
    double det = m[0]*c00 + m[1]*c01 + m[2]*c02;
    double id  = 1.0 / det;
    o[0] = c00 * id;
    o[1] = (m[2]*m[7] - m[1]*m[8]) * id;
    o[2] = (m[1]*m[5] - m[2]*m[4]) * id;
    o[3] = c01 * id;
    o[4] = (m[0]*m[8] - m[2]*m[6]) * id;
    o[5] = (m[2]*m[3] - m[0]*m[5]) * id;
    o[6] = c02 * id;
    o[7] = (m[1]*m[6] - m[0]*m[7]) * id;
    o[8] = (m[0]*m[4] - m[1]*m[3]) * id;
}

__global__ void prep_kernel(const float* __restrict__ l2i,
                            const float* __restrict__ lam,
                            double* __restrict__ W) {
    int t = threadIdx.x;
    if (t < NB) {
        const float* Lb = lam + t * 16;
        double m[9];
        for (int i = 0; i < 3; ++i)
            for (int j = 0; j < 3; ++j) m[i*3+j] = (double)Lb[i*4+j];
        inv3x3(m, W + OFF_INVLAM + t*9);
        for (int i = 0; i < 3; ++i) W[OFF_LAMT + t*3 + i] = (double)Lb[i*4+3];
    }
    if (t < NB*NCAM) {
        int c = t % NCAM;
        const float* Mb = l2i + t * 16;
        double m[9], tv[3];
        for (int i = 0; i < 3; ++i) {
            // faithful replication of the cumulative scale_intrinsics bug:
            // cam0 rows 0,2 divided by 8; cam1 rows 1,2 by 64; cams>=2 untouched
            double s = 1.0;
            if (c == 0 && (i == 0 || i == 2)) s = 0.125;
            if (c == 1 && (i == 1 || i == 2)) s = 0.015625;
            for (int j = 0; j < 3; ++j) m[i*3+j] = (double)Mb[i*4+j] * s;
            tv[i] = (double)Mb[i*4+3] * s;
        }
        inv3x3(m, W + OFF_INVM + t*9);
        for (int i = 0; i < 3; ++i) W[OFF_TSCL + t*3 + i] = tv[i];
    }
}

__global__ void init_win(int* __restrict__ win) {
    int i = blockIdx.x * blockDim.x + threadIdx.x;
    if (i < NB*NCAM*NCELL) win[i] = -1;
}

__global__ void project_kernel(const float* __restrict__ pts,
                               const float* __restrict__ l2i,
                               const float* __restrict__ iam,
                               const double* __restrict__ W,
                               int* __restrict__ win) {
    int idx = blockIdx.x * blockDim.x + threadIdx.x;
    if (idx >= NB*NPTS) return;
    int b = idx / NPTS;
    int n = idx - b * NPTS;

    const float4 p4 = ((const float4*)pts)[idx];
    double px = (double)p4.x - W[OFF_LAMT + b*3 + 0];
    double py = (double)p4.y - W[OFF_LAMT + b*3 + 1];
    double pz = (double)p4.z - W[OFF_LAMT + b*3 + 2];
    const double* IL = W + OFF_INVLAM + b*9;
    double cxv = IL[0]*px + IL[1]*py + IL[2]*pz;
    double cyv = IL[3]*px + IL[4]*py + IL[5]*pz;
    double czv = IL[6]*px + IL[7]*py + IL[8]*pz;

    for (int c = 0; c < NCAM; ++c) {
        int bc = b * NCAM + c;
        const float* L = l2i + bc * 16;
        double camx = (double)L[0]*cxv + (double)L[1]*cyv + (double)L[2] *czv + (double)L[3];
        double camy = (double)L[4]*cxv + (double)L[5]*cyv + (double)L[6] *czv + (double)L[7];
        double camz = (double)L[8]*cxv + (double)L[9]*cyv + (double)L[10]*czv + (double)L[11];
        double d = fmin(fmax(camz, 1e-5), 1e5);
        double uvx = camx / d;
        double uvy = camy / d;
        // img_aug_matrix application (identity in data, kept for generality)
        const float* A = iam + bc * 16;
        double q0 = (double)A[0]*uvx + (double)A[1]*uvy + (double)A[2]*d + (double)A[3];
        double q1 = (double)A[4]*uvx + (double)A[5]*uvy + (double)A[6]*d + (double)A[7];
        double c0 = q1;   // coords[...,1]
        double c1 = q0;   // coords[...,0]
        if (!((c0 >= 0.0) && (c0 < 256.0) && (c1 >= 0.0) && (c1 < 704.0))) continue;
        double u = c0 / 8.0;
        double v = c1 / 8.0;
        if (!((u >= 0.0) && (u < (double)FH) && (v >= 0.0) && (v < (double)FW))) continue;

        const double* IM = W + OFF_INVM + bc*9;
        const double* TS = W + OFF_TSCL + bc*3;
        double g0 = u * d - TS[0];
        double g1 = v * d - TS[1];
        double g2 = d     - TS[2];
        double X = IM[0]*g0 + IM[1]*g1 + IM[2]*g2;
        double Y = IM[3]*g0 + IM[4]*g1 + IM[5]*g2;
        double Z = IM[6]*g0 + IM[7]*g1 + IM[8]*g2;
        double xl = trunc(X);
        double yl = trunc(Y);
        if (!((Z >= 0.0) && (xl >= -54.0) && (yl >= -54.0) && (xl < 54.0) && (yl < 54.0)))
            continue;

        int ui = (int)u;            // trunc toward zero, u in [0,32)
        int vi = (int)v;            // v in [0,88)
        int xi = (int)(xl / 0.3);   // trunc toward zero
        int yi = (int)(yl / 0.3);
        if (xi < 0) xi += BEVN;     // torch negative-index wraparound
        if (yi < 0) yi += BEVN;
        if (xi < 0 || xi >= BEVN || yi < 0 || yi >= BEVN) continue;  // mode='drop'

        // last valid point index wins (XLA CPU scatter-set applies updates in order);
        // n is unique per (b,cam) so atomicMax over packed (n | ui | vi) == last write.
        int packed = (n << 12) | (ui << 7) | vi;
        atomicMax(&win[bc * NCELL + xi * BEVN + yi], packed);
    }
}

__global__ void emit_kernel(const float* __restrict__ feat,
                            const int* __restrict__ win,
                            float* __restrict__ out) {
    __shared__ int   sbase[32][NCAM];
    __shared__ float sacc[32][81];   // 81 stride: odd vs 32 banks -> conflict-free
    int b = blockIdx.y;
    int cell0 = blockIdx.x * 32;
    int t = threadIdx.x;

    if (t < 32 * NCAM) {
        int celli = t / NCAM, c = t % NCAM;
        int cell = cell0 + celli;
        int base = -1;
        if (cell < NCELL) {
            int w = win[(b * NCAM + c) * NCELL + cell];
            if (w >= 0) {
                int ui = (w >> 7) & 31;
                int vi = w & 127;
                base = ((b * NCAM + c) * CFEAT) * (FH * FW) + ui * FW + vi;
            }
        }
        sbase[celli][c] = base;
    }
    __syncthreads();

    int celli = t & 31;
    int sub   = t >> 5;              // 0..7, 10 channels each
    for (int k = 0; k < 10; ++k) {
        int ch = sub * 10 + k;
        float acc = 0.0f;
        for (int c = 0; c < NCAM; ++c) {
            int base = sbase[celli][c];
            if (base >= 0) acc += feat[base + ch * (FH * FW)];
        }
        sacc[celli][ch] = acc;
    }
    __syncthreads();

    for (int w = t; w < 32 * CFEAT; w += 256) {
        int ch = w >> 5, ci = w & 31;
        int cell = cell0 + ci;
        if (cell < NCELL)
            out[(b * CFEAT + ch) * NCELL + cell] = sacc[ci][ch];
    }
}

extern "C" void kernel_launch(void* const* d_in, const int* in_sizes, int n_in,
                              void* d_out, int out_size, void* d_ws, size_t ws_size,
                              hipStream_t stream) {
    const float* img_feat = (const float*)d_in[0];  // (B,NC,C,FH,FW) f32
    const float* points   = (const float*)d_in[1];  // (B,N,4) f32
    const float* l2i      = (const float*)d_in[2];  // (B,NC,4,4) f32
    const float* iam      = (const float*)d_in[3];  // (B,NC,4,4) f32
    const float* lam      = (const float*)d_in[4];  // (B,4,4) f32

    double* W   = (double*)d_ws;
    int*    win = (int*)((char*)d_ws + WIN_BYTE_OFF);

    hipLaunchKernelGGL(prep_kernel, dim3(1), dim3(64), 0, stream, l2i, lam, W);

    int nw = NB * NCAM * NCELL;
    hipLaunchKernelGGL(init_win, dim3((nw + 255) / 256), dim3(256), 0, stream, win);

    hipLaunchKernelGGL(project_kernel, dim3((NB * NPTS + 255) / 256), dim3(256), 0, stream,
                       points, l2i, iam, W, win);

    hipLaunchKernelGGL(emit_kernel, dim3((NCELL + 31) / 32, NB), dim3(256), 0, stream,
                       img_feat, win, (float*)d_out);
}

// Round 2
// 69.263 us; speedup vs baseline: 1.0524x; 1.0524x over previous
//
#include <hip/hip_runtime.h>

#define NB    2
#define NCAM  6
#define CFEAT 80
#define FH    32
#define FW    88
#define FHW   (FH*FW)          // 2816
#define NPTS  150000
#define BEVN  180
#define NCELL (BEVN*BEVN)      // 32400

// ---- ws layout ----
// doubles at byte offset 0:
//   invLam : NB*9            (inverse of lidar_aug 3x3, f64)
//   lamT   : NB*3            (lidar_aug translation)
//   invM   : NB*NCAM*9       (inverse of buggy-scaled lidar2image 3x3)
//   tScl   : NB*NCAM*3       (buggy-scaled translation)
// int32 at byte offset 4096:
//   win    : NB*NCAM*NCELL   (packed winner per BEV cell, -1 = none)
// float  at byte offset FEATT_OFF (if ws large enough):
//   featT  : NB*NCAM*FHW*CFEAT  (channel-last transposed features)
#define OFF_INVLAM 0
#define OFF_LAMT   (OFF_INVLAM + NB*9)
#define OFF_INVM   (OFF_LAMT + NB*3)
#define OFF_TSCL   (OFF_INVM + NB*NCAM*9)
#define WIN_BYTE_OFF 4096
#define WIN_BYTES  (NB*NCAM*NCELL*4)                 // 1,555,200
#define FEATT_OFF  ((size_t)(WIN_BYTE_OFF + WIN_BYTES + 255) & ~(size_t)255)
#define FEATT_BYTES ((size_t)NB*NCAM*FHW*CFEAT*4)    // 10,813,440

__device__ inline void inv3x3(const double m[9], double* o) {
    double c00 = m[4]*m[8] - m[5]*m[7];
    double c01 = m[5]*m[6] - m[3]*m[8];
    double c02 = m[3]*m[7] - m[4]*m[6];
    double det = m[0]*c00 + m[1]*c01 + m[2]*c02;
    double id  = 1.0 / det;
    o[0] = c00 * id;
    o[1] = (m[2]*m[7] - m[1]*m[8]) * id;
    o[2] = (m[1]*m[5] - m[2]*m[4]) * id;
    o[3] = c01 * id;
    o[4] = (m[0]*m[8] - m[2]*m[6]) * id;
    o[5] = (m[2]*m[3] - m[0]*m[5]) * id;
    o[6] = c02 * id;
    o[7] = (m[1]*m[6] - m[0]*m[7]) * id;
    o[8] = (m[0]*m[4] - m[1]*m[3]) * id;
}

__device__ inline void prep_body(int t, const float* __restrict__ l2i,
                                 const float* __restrict__ lam,
                                 double* __restrict__ W) {
    if (t < NB) {
        const float* Lb = lam + t * 16;
        double m[9];
        for (int i = 0; i < 3; ++i)
            for (int j = 0; j < 3; ++j) m[i*3+j] = (double)Lb[i*4+j];
        inv3x3(m, W + OFF_INVLAM + t*9);
        for (int i = 0; i < 3; ++i) W[OFF_LAMT + t*3 + i] = (double)Lb[i*4+3];
    }
    if (t < NB*NCAM) {
        int c = t % NCAM;
        const float* Mb = l2i + t * 16;
        double m[9], tv[3];
        for (int i = 0; i < 3; ++i) {
            // faithful replication of the cumulative scale_intrinsics bug:
            // cam0 rows 0,2 divided by 8; cam1 rows 1,2 by 64; cams>=2 untouched
            double s = 1.0;
            if (c == 0 && (i == 0 || i == 2)) s = 0.125;
            if (c == 1 && (i == 1 || i == 2)) s = 0.015625;
            for (int j = 0; j < 3; ++j) m[i*3+j] = (double)Mb[i*4+j] * s;
            tv[i] = (double)Mb[i*4+3] * s;
        }
        inv3x3(m, W + OFF_INVM + t*9);
        for (int i = 0; i < 3; ++i) W[OFF_TSCL + t*3 + i] = tv[i];
    }
}

__global__ void prep_kernel(const float* __restrict__ l2i,
                            const float* __restrict__ lam,
                            double* __restrict__ W) {
    prep_body(threadIdx.x, l2i, lam, W);
}

// Transpose (b,c,ch,fh,fw) -> (b,c,fh,fw,ch); block(0,0) also runs prep.
__global__ void transpose_prep_kernel(const float* __restrict__ feat,
                                      float* __restrict__ featT,
                                      const float* __restrict__ l2i,
                                      const float* __restrict__ lam,
                                      double* __restrict__ W) {
    if (blockIdx.x == 0 && blockIdx.y == 0 && threadIdx.x < 64)
        prep_body(threadIdx.x, l2i, lam, W);

    __shared__ float tile[CFEAT * 65];   // stride 65: bank = (ch + j) % 32
    int bc = blockIdx.y;
    int s0 = blockIdx.x * 64;            // FHW = 44 * 64 exactly
    int t  = threadIdx.x;

    int j   = t & 63;
    int ch0 = t >> 6;                    // 0..3
    for (int ch = ch0; ch < CFEAT; ch += 4)
        tile[ch * 65 + j] = feat[(bc * CFEAT + ch) * FHW + s0 + j];
    __syncthreads();

    for (int w = t; w < 64 * CFEAT; w += 256) {
        int jj = w / CFEAT, ch = w % CFEAT;
        featT[((size_t)bc * FHW + s0 + jj) * CFEAT + ch] = tile[ch * 65 + jj];
    }
}

// One thread per (b,cam,point). blockIdx.y = b*NCAM + c (wave-uniform matrices).
__global__ void project_kernel(const float* __restrict__ pts,
                               const float* __restrict__ l2i,
                               const float* __restrict__ iam,
                               const double* __restrict__ W,
                               int* __restrict__ win) {
    int n  = blockIdx.x * blockDim.x + threadIdx.x;
    if (n >= NPTS) return;
    int bc = blockIdx.y;
    int b  = bc / NCAM;

    const float4 p4 = ((const float4*)pts)[b * NPTS + n];
    double px = (double)p4.x - W[OFF_LAMT + b*3 + 0];
    double py = (double)p4.y - W[OFF_LAMT + b*3 + 1];
    double pz = (double)p4.z - W[OFF_LAMT + b*3 + 2];
    const double* IL = W + OFF_INVLAM + b*9;
    double cxv = IL[0]*px + IL[1]*py + IL[2]*pz;
    double cyv = IL[3]*px + IL[4]*py + IL[5]*pz;
    double czv = IL[6]*px + IL[7]*py + IL[8]*pz;

    const float* L = l2i + bc * 16;
    double camx = (double)L[0]*cxv + (double)L[1]*cyv + (double)L[2] *czv + (double)L[3];
    double camy = (double)L[4]*cxv + (double)L[5]*cyv + (double)L[6] *czv + (double)L[7];
    double camz = (double)L[8]*cxv + (double)L[9]*cyv + (double)L[10]*czv + (double)L[11];
    double d = fmin(fmax(camz, 1e-5), 1e5);
    double uvx = camx / d;
    double uvy = camy / d;
    // img_aug_matrix application (identity in data, kept for generality)
    const float* A = iam + bc * 16;
    double q0 = (double)A[0]*uvx + (double)A[1]*uvy + (double)A[2]*d + (double)A[3];
    double q1 = (double)A[4]*uvx + (double)A[5]*uvy + (double)A[6]*d + (double)A[7];
    double c0 = q1;   // coords[...,1]
    double c1 = q0;   // coords[...,0]
    if (!((c0 >= 0.0) && (c0 < 256.0) && (c1 >= 0.0) && (c1 < 704.0))) return;
    double u = c0 * 0.125;   // /8 exact
    double v = c1 * 0.125;
    if (!((u >= 0.0) && (u < (double)FH) && (v >= 0.0) && (v < (double)FW))) return;

    const double* IM = W + OFF_INVM + bc*9;
    const double* TS = W + OFF_TSCL + bc*3;
    double g0 = u * d - TS[0];
    double g1 = v * d - TS[1];
    double g2 = d     - TS[2];
    double X = IM[0]*g0 + IM[1]*g1 + IM[2]*g2;
    double Y = IM[3]*g0 + IM[4]*g1 + IM[5]*g2;
    double Z = IM[6]*g0 + IM[7]*g1 + IM[8]*g2;
    double xl = trunc(X);
    double yl = trunc(Y);
    if (!((Z >= 0.0) && (xl >= -54.0) && (yl >= -54.0) && (xl < 54.0) && (yl < 54.0)))
        return;

    int ui = (int)u;            // trunc toward zero, u in [0,32)
    int vi = (int)v;            // v in [0,88)
    // trunc(xl/0.3) for integer xl == C integer division (10*xl)/3:
    // 0.3_f64 < 3/10 so fl(xl/0.3) lands strictly on the correct side of every
    // integer boundary for xl in [-54,53] (margin >= 1/3 ulp-free); proven exact.
    int ixl = (int)xl, iyl = (int)yl;
    int xi = (10 * ixl) / 3;
    int yi = (10 * iyl) / 3;
    if (xi < 0) xi += BEVN;     // torch negative-index wraparound
    if (yi < 0) yi += BEVN;
    if (xi < 0 || xi >= BEVN || yi < 0 || yi >= BEVN) return;  // mode='drop'

    // last valid point index wins; n unique per (b,cam) so atomicMax over
    // packed (n | ui | vi) == last write.
    int packed = (n << 12) | (ui << 7) | vi;
    atomicMax(&win[bc * NCELL + xi * BEVN + yi], packed);
}

// Emit from transposed features (channel-last, contiguous 320B per winner).
__global__ void emit_t_kernel(const float* __restrict__ featT,
                              const int* __restrict__ win,
                              float* __restrict__ out) {
    __shared__ int   sbase[NCAM][32];
    __shared__ float sacc[CFEAT][33];
    int b = blockIdx.y;
    int cell0 = blockIdx.x * 32;
    int t = threadIdx.x;

    if (t < 32 * NCAM) {
        int c = t >> 5, celli = t & 31;
        int cell = cell0 + celli;
        int base = -1;
        if (cell < NCELL) {
            int w = win[(b * NCAM + c) * NCELL + cell];
            if (w >= 0) {
                int ui = (w >> 7) & 31;
                int vi = w & 127;
                base = ((b * NCAM + c) * FHW + ui * FW + vi) * CFEAT;
            }
        }
        sbase[c][celli] = base;
    }
    __syncthreads();

    int celli = t >> 3;          // 0..31
    int sub   = t & 7;           // 0..7 -> 10 channels each
    float acc[10];
#pragma unroll
    for (int k = 0; k < 10; ++k) acc[k] = 0.0f;
    for (int c = 0; c < NCAM; ++c) {
        int base = sbase[c][celli];
        if (base >= 0) {
#pragma unroll
            for (int k = 0; k < 10; ++k)
                acc[k] += featT[base + sub * 10 + k];
        }
    }
#pragma unroll
    for (int k = 0; k < 10; ++k) sacc[sub * 10 + k][celli] = acc[k];
    __syncthreads();

    for (int w = t; w < 32 * CFEAT; w += 256) {
        int ch = w >> 5, ci = w & 31;
        int cell = cell0 + ci;
        if (cell < NCELL)
            out[(b * CFEAT + ch) * NCELL + cell] = sacc[ch][ci];
    }
}

// Fallback emit from original layout (if ws too small for featT).
__global__ void emit_kernel(const float* __restrict__ feat,
                            const int* __restrict__ win,
                            float* __restrict__ out) {
    __shared__ int   sbase[32][NCAM];
    __shared__ float sacc[32][81];
    int b = blockIdx.y;
    int cell0 = blockIdx.x * 32;
    int t = threadIdx.x;

    if (t < 32 * NCAM) {
        int celli = t / NCAM, c = t % NCAM;
        int cell = cell0 + celli;
        int base = -1;
        if (cell < NCELL) {
            int w = win[(b * NCAM + c) * NCELL + cell];
            if (w >= 0) {
                int ui = (w >> 7) & 31;
                int vi = w & 127;
                base = ((b * NCAM + c) * CFEAT) * FHW + ui * FW + vi;
            }
        }
        sbase[celli][c] = base;
    }
    __syncthreads();

    int celli = t & 31;
    int sub   = t >> 5;
    for (int k = 0; k < 10; ++k) {
        int ch = sub * 10 + k;
        float acc = 0.0f;
        for (int c = 0; c < NCAM; ++c) {
            int base = sbase[celli][c];
            if (base >= 0) acc += feat[base + ch * FHW];
        }
        sacc[celli][ch] = acc;
    }
    __syncthreads();

    for (int w = t; w < 32 * CFEAT; w += 256) {
        int ch = w >> 5, ci = w & 31;
        int cell = cell0 + ci;
        if (cell < NCELL)
            out[(b * CFEAT + ch) * NCELL + cell] = sacc[ci][ch];
    }
}

extern "C" void kernel_launch(void* const* d_in, const int* in_sizes, int n_in,
                              void* d_out, int out_size, void* d_ws, size_t ws_size,
                              hipStream_t stream) {
    const float* img_feat = (const float*)d_in[0];  // (B,NC,C,FH,FW) f32
    const float* points   = (const float*)d_in[1];  // (B,N,4) f32
    const float* l2i      = (const float*)d_in[2];  // (B,NC,4,4) f32
    const float* iam      = (const float*)d_in[3];  // (B,NC,4,4) f32
    const float* lam      = (const float*)d_in[4];  // (B,4,4) f32

    double* W     = (double*)d_ws;
    int*    win   = (int*)((char*)d_ws + WIN_BYTE_OFF);
    float*  featT = (float*)((char*)d_ws + FEATT_OFF);
    bool use_t = ws_size >= FEATT_OFF + FEATT_BYTES;

    hipMemsetAsync(win, 0xFF, WIN_BYTES, stream);   // all cells -> -1

    if (use_t) {
        hipLaunchKernelGGL(transpose_prep_kernel, dim3(FHW / 64, NB * NCAM), dim3(256), 0,
                           stream, img_feat, featT, l2i, lam, W);
    } else {
        hipLaunchKernelGGL(prep_kernel, dim3(1), dim3(64), 0, stream, l2i, lam, W);
    }

    hipLaunchKernelGGL(project_kernel, dim3((NPTS + 255) / 256, NB * NCAM), dim3(256), 0,
                       stream, points, l2i, iam, W, win);

    if (use_t) {
        hipLaunchKernelGGL(emit_t_kernel, dim3((NCELL + 31) / 32, NB), dim3(256), 0,
                           stream, featT, win, (float*)d_out);
    } else {
        hipLaunchKernelGGL(emit_kernel, dim3((NCELL + 31) / 32, NB), dim3(256), 0,
                           stream, img_feat, win, (float*)d_out);
    }
}

// Round 3
// 58.074 us; speedup vs baseline: 1.2552x; 1.1927x over previous
//
#include <hip/hip_runtime.h>

#define NB    2
#define NCAM  6
#define CFEAT 80
#define FH    32
#define FW    88
#define FHW   (FH*FW)          // 2816
#define NPTS  150000
#define BEVN  180
#define NCELL (BEVN*BEVN)      // 32400
#define NWIN  (NB*NCAM*NCELL)  // 388800

#define NREG    587            // ceil(NPTS/256) point-regions per batch
#define LSTRIDE (NREG*256)     // 150272 list slots per (b,cam)
#define TBLK    528            // transpose blocks: 44 * 12
#define GRID_A  (TBLK + NB*NREG)   // 1702

// ---- ws layout ----
// f64 W at 0:
//   per b (12 dbl):  invLam 9, lamT 3                      -> W[b*12 ..]
//   per bc (32 dbl) at OFF_CAM: L2row 4 | FB0,fb0 4 | FB1,fb1 4 | A02,A03,A12,A13 4 |
//                               Px 5 | Py 5 | Pz 5 (folded unprojection polys)
#define OFF_CAM   (NB*12)
#define WIN_BYTE_OFF 4096
#define WIN_BYTES  (NWIN*4)                          // 1,555,200
#define FEATT_OFF  ((size_t)(WIN_BYTE_OFF + WIN_BYTES + 255) & ~(size_t)255)
#define FEATT_BYTES ((size_t)NB*NCAM*FHW*CFEAT*4)    // 10,813,440
#define LIST_OFF   ((FEATT_OFF + FEATT_BYTES + 255) & ~(size_t)255)
#define LIST_BYTES ((size_t)NB*NCAM*LSTRIDE*4)       // 7,213,056
#define CNT_OFF    ((LIST_OFF + LIST_BYTES + 255) & ~(size_t)255)
#define CNT_BYTES  ((size_t)NB*NCAM*NREG*4)
#define WS_NEED    (CNT_OFF + CNT_BYTES)

__device__ inline void inv3x3(const double m[9], double* o) {
    double c00 = m[4]*m[8] - m[5]*m[7];
    double c01 = m[5]*m[6] - m[3]*m[8];
    double c02 = m[3]*m[7] - m[4]*m[6];
    double det = m[0]*c00 + m[1]*c01 + m[2]*c02;
    double id  = 1.0 / det;
    o[0] = c00 * id;
    o[1] = (m[2]*m[7] - m[1]*m[8]) * id;
    o[2] = (m[1]*m[5] - m[2]*m[4]) * id;
    o[3] = c01 * id;
    o[4] = (m[0]*m[8] - m[2]*m[6]) * id;
    o[5] = (m[2]*m[3] - m[0]*m[5]) * id;
    o[6] = c02 * id;
    o[7] = (m[1]*m[6] - m[0]*m[7]) * id;
    o[8] = (m[0]*m[4] - m[1]*m[3]) * id;
}

__device__ inline void inv3x3f(const float m[9], float* o) {
    float c00 = m[4]*m[8] - m[5]*m[7];
    float c01 = m[5]*m[6] - m[3]*m[8];
    float c02 = m[3]*m[7] - m[4]*m[6];
    float det = m[0]*c00 + m[1]*c01 + m[2]*c02;
    float id  = 1.0f / det;
    o[0] = c00 * id;
    o[1] = (m[2]*m[7] - m[1]*m[8]) * id;
    o[2] = (m[1]*m[5] - m[2]*m[4]) * id;
    o[3] = c01 * id;
    o[4] = (m[0]*m[8] - m[2]*m[6]) * id;
    o[5] = (m[2]*m[3] - m[0]*m[5]) * id;
    o[6] = c02 * id;
    o[7] = (m[1]*m[6] - m[0]*m[7]) * id;
    o[8] = (m[0]*m[4] - m[1]*m[3]) * id;
}

// Full f64 prep: invLam/lamT per b; per-cam folded coefficients.
__device__ void prep_full(int t, const float* __restrict__ l2i,
                          const float* __restrict__ iam,
                          const float* __restrict__ lam,
                          double* __restrict__ W) {
    if (t < NB) {
        const float* Lb = lam + t * 16;
        double m[9];
        for (int i = 0; i < 3; ++i)
            for (int j = 0; j < 3; ++j) m[i*3+j] = (double)Lb[i*4+j];
        inv3x3(m, W + t*12);
        for (int i = 0; i < 3; ++i) W[t*12 + 9 + i] = (double)Lb[i*4+3];
    }
    if (t < NB*NCAM) {
        int c = t % NCAM;
        const float* L = l2i + t * 16;
        const float* A = iam + t * 16;
        double* K = W + OFF_CAM + t * 32;
        // projection pieces (unscaled l2i)
        K[0]=(double)L[8]; K[1]=(double)L[9]; K[2]=(double)L[10]; K[3]=(double)L[11];
        for (int j = 0; j < 4; ++j) {
            K[4+j] = (double)A[0]*(double)L[j] + (double)A[1]*(double)L[4+j]; // FB0,fb0
            K[8+j] = (double)A[4]*(double)L[j] + (double)A[5]*(double)L[4+j]; // FB1,fb1
        }
        K[12]=(double)A[2]; K[13]=(double)A[3]; K[14]=(double)A[6]; K[15]=(double)A[7];
        // buggy-scaled matrix + inverse (scale_intrinsics bug replication)
        double ms[9], ts[3];
        for (int i = 0; i < 3; ++i) {
            double s = 1.0;
            if (c == 0 && (i == 0 || i == 2)) s = 0.125;
            if (c == 1 && (i == 1 || i == 2)) s = 0.015625;
            for (int j = 0; j < 3; ++j) ms[i*3+j] = (double)L[i*4+j] * s;
            ts[i] = (double)L[i*4+3] * s;
        }
        double IM[9];
        inv3x3(ms, IM);
        // folded, division-free unprojection:
        //  row(X) = P0*n1 + P1*n0 + PD2*d^2 + PD*d + PC
        //  where u*d = (n1 + A12 d^2 + A13 d)/8, v*d = (n0 + A02 d^2 + A03 d)/8
        for (int rw = 0; rw < 3; ++rw) {
            double P0 = IM[rw*3+0] * 0.125;
            double P1 = IM[rw*3+1] * 0.125;
            double I2 = IM[rw*3+2];
            K[16 + rw*5 + 0] = P0;
            K[16 + rw*5 + 1] = P1;
            K[16 + rw*5 + 2] = P0*(double)A[6] + P1*(double)A[2];          // x d^2
            K[16 + rw*5 + 3] = P0*(double)A[7] + P1*(double)A[3] + I2;     // x d
            K[16 + rw*5 + 4] = -(IM[rw*3+0]*ts[0] + IM[rw*3+1]*ts[1] + IM[rw*3+2]*ts[2]);
        }
    }
}

// Conservative f32 frustum filter. C = 16 floats:
// [0..3] L2row  [4..7] FB0,fb0  [8..11] FB1,fb1  [12..15] A02,A03,A12,A13
// Must NEVER reject a (point,cam) that is truly on-image (margins cover all
// f32 error incl. worst-case dot-product cancellation ~0.03; floor 0.5 = 20x).
__device__ inline bool filt(float cv0, float cv1, float cv2, const float* C) {
    float zc = C[0]*cv0 + C[1]*cv1 + C[2]*cv2 + C[3];
    float n0 = C[4]*cv0 + C[5]*cv1 + C[6]*cv2 + C[7];
    float n1 = C[8]*cv0 + C[9]*cv1 + C[10]*cv2 + C[11];
    if (zc >= 1e-3f) {
        float w0 = n0 + (C[12]*zc + C[13]) * zc;
        float w1 = n1 + (C[14]*zc + C[15]) * zc;
        float m0 = 0.5f + 2e-4f * (fabsf(w0) + 704.0f * zc);
        float m1 = 0.5f + 2e-4f * (fabsf(w1) + 256.0f * zc);
        return (w0 > -m0) && (w0 < 704.0f*zc + m0) && (w1 > -m1) && (w1 < 256.0f*zc + m1);
    }
    // behind/near camera plane: d <= ~1.1e-3 -> |n| <= 704*d + err < 2
    return (fabsf(n0) < 2.0f) && (fabsf(n1) < 2.0f);
}

// Fused: win-init + transpose (blocks 0..TBLK-1, block 0 also f64 prep)
//        + phase-A filter/compaction (blocks TBLK..)
__global__ void fusedA_kernel(const float* __restrict__ feat,
                              float* __restrict__ featT,
                              const float* __restrict__ pts,
                              const float* __restrict__ l2i,
                              const float* __restrict__ iam,
                              const float* __restrict__ lam,
                              double* __restrict__ W,
                              int* __restrict__ win,
                              unsigned int* __restrict__ list,
                              int* __restrict__ cnt) {
    __shared__ float tile[CFEAT * 65];
    __shared__ float s_fc[NCAM][16];
    __shared__ float s_il[12];
    __shared__ int   s_wcnt[NCAM][4];
    __shared__ int   s_woff[NCAM][4];

    int bx = blockIdx.x;
    int t  = threadIdx.x;

    // win init (all blocks, one shot)
    { int i = bx * 256 + t; if (i < NWIN) win[i] = -1; }

    if (bx < TBLK) {
        if (bx == 0 && t < 64) prep_full(t, l2i, iam, lam, W);
        // transpose (b,c,ch,fh,fw) -> (b,c,fh,fw,ch)
        int bc = bx / 44;
        int s0 = (bx % 44) * 64;
        int j   = t & 63;
        int ch0 = t >> 6;
        for (int ch = ch0; ch < CFEAT; ch += 4)
            tile[ch * 65 + j] = feat[(bc * CFEAT + ch) * FHW + s0 + j];
        __syncthreads();
        for (int w = t; w < 64 * CFEAT; w += 256) {
            int jj = w / CFEAT, ch = w % CFEAT;
            featT[((size_t)bc * FHW + s0 + jj) * CFEAT + ch] = tile[ch * 65 + jj];
        }
        return;
    }

    // ---- phase A: f32 filter + block-level compaction (no atomics) ----
    int r0 = bx - TBLK;
    int b  = r0 / NREG;
    int r  = r0 - b * NREG;

    if (t == 0) {
        const float* Lb = lam + b * 16;
        float m[9];
        for (int i = 0; i < 3; ++i)
            for (int j = 0; j < 3; ++j) m[i*3+j] = Lb[i*4+j];
        inv3x3f(m, s_il);
        for (int i = 0; i < 3; ++i) s_il[9+i] = Lb[i*4+3];
        for (int c = 0; c < NCAM; ++c) {
            const float* L = l2i + (b*NCAM + c) * 16;
            const float* A = iam + (b*NCAM + c) * 16;
            s_fc[c][0]=L[8]; s_fc[c][1]=L[9]; s_fc[c][2]=L[10]; s_fc[c][3]=L[11];
            for (int j = 0; j < 4; ++j) {
                s_fc[c][4+j] = A[0]*L[j] + A[1]*L[4+j];
                s_fc[c][8+j] = A[4]*L[j] + A[5]*L[4+j];
            }
            s_fc[c][12]=A[2]; s_fc[c][13]=A[3]; s_fc[c][14]=A[6]; s_fc[c][15]=A[7];
        }
    }
    __syncthreads();

    int n = r * 256 + t;
    bool ok = (n < NPTS);
    float cv0 = 0.f, cv1 = 0.f, cv2 = 0.f;
    if (ok) {
        float4 p = ((const float4*)pts)[b * NPTS + n];
        float pm0 = p.x - s_il[9], pm1 = p.y - s_il[10], pm2 = p.z - s_il[11];
        cv0 = s_il[0]*pm0 + s_il[1]*pm1 + s_il[2]*pm2;
        cv1 = s_il[3]*pm0 + s_il[4]*pm1 + s_il[5]*pm2;
        cv2 = s_il[6]*pm0 + s_il[7]*pm1 + s_il[8]*pm2;
    }

    unsigned long long bm[NCAM];
    int lane = t & 63, wid = t >> 6;
#pragma unroll
    for (int c = 0; c < NCAM; ++c) {
        bool pass = ok && filt(cv0, cv1, cv2, s_fc[c]);
        bm[c] = __ballot(pass);
        if (lane == 0) s_wcnt[c][wid] = __popcll(bm[c]);
    }
    __syncthreads();
    if (t < NCAM) {
        int c = t;
        int a0 = s_wcnt[c][0], a1 = s_wcnt[c][1], a2 = s_wcnt[c][2], a3 = s_wcnt[c][3];
        s_woff[c][0] = 0; s_woff[c][1] = a0; s_woff[c][2] = a0+a1; s_woff[c][3] = a0+a1+a2;
        cnt[(b*NCAM + c) * NREG + r] = a0+a1+a2+a3;
    }
    __syncthreads();
    unsigned long long ltmask = (lane == 63) ? ~0ull >> 1 : ((1ull << (lane)) - 1);
#pragma unroll
    for (int c = 0; c < NCAM; ++c) {
        if ((bm[c] >> lane) & 1ull) {
            int pos = s_woff[c][wid] + __popcll(bm[c] & ((1ull << lane) - 1ull));
            list[((size_t)(b*NCAM + c)) * LSTRIDE + r * 256 + pos] = (unsigned int)n;
        }
    }
    (void)ltmask;
}

// Phase C: one wave per (bc, region). Camera-uniform, exact f64 decisions.
__global__ void __launch_bounds__(64) proj2_kernel(const float* __restrict__ pts,
                                                   const double* __restrict__ W,
                                                   const unsigned int* __restrict__ list,
                                                   const int* __restrict__ cnt,
                                                   int* __restrict__ win) {
    int bc = blockIdx.y;
    int r  = blockIdx.x;
    int tot = cnt[bc * NREG + r];
    if (tot == 0) return;
    int b = bc / NCAM;
    const double* IL = W + b * 12;
    const double* K  = W + OFF_CAM + bc * 32;
    int lane = threadIdx.x;

    for (int i = lane; i < tot; i += 64) {
        unsigned int n = list[(size_t)bc * LSTRIDE + r * 256 + i];
        float4 p = ((const float4*)pts)[b * NPTS + n];
        double pm0 = (double)p.x - IL[9];
        double pm1 = (double)p.y - IL[10];
        double pm2 = (double)p.z - IL[11];
        double cv0 = IL[0]*pm0 + IL[1]*pm1 + IL[2]*pm2;
        double cv1 = IL[3]*pm0 + IL[4]*pm1 + IL[5]*pm2;
        double cv2 = IL[6]*pm0 + IL[7]*pm1 + IL[8]*pm2;

        double zc = K[0]*cv0 + K[1]*cv1 + K[2]*cv2 + K[3];
        double d  = fmin(fmax(zc, 1e-5), 1e5);
        double inv_d = 1.0 / d;
        double n0 = K[4]*cv0 + K[5]*cv1 + K[6]*cv2 + K[7];
        double n1 = K[8]*cv0 + K[9]*cv1 + K[10]*cv2 + K[11];
        double c1 = n0 * inv_d + (K[12]*d + K[13]);   // col coord, [0,704)
        double c0 = n1 * inv_d + (K[14]*d + K[15]);   // row coord, [0,256)
        if (!((c0 >= 0.0) && (c0 < 256.0) && (c1 >= 0.0) && (c1 < 704.0))) continue;
        // u = c0/8 in [0,32), v = c1/8 in [0,88): exact /8 => uv checks redundant

        double dd = d * d;
        double X = K[16]*n1 + K[17]*n0 + K[18]*dd + K[19]*d + K[20];
        double Y = K[21]*n1 + K[22]*n0 + K[23]*dd + K[24]*d + K[25];
        double Z = K[26]*n1 + K[27]*n0 + K[28]*dd + K[29]*d + K[30];
        double xl = trunc(X);
        double yl = trunc(Y);
        if (!((Z >= 0.0) && (xl >= -54.0) && (yl >= -54.0) && (xl < 54.0) && (yl < 54.0)))
            continue;

        int ui = (int)(c0 * 0.125);
        int vi = (int)(c1 * 0.125);
        int xi = (10 * (int)xl) / 3;   // == trunc(xl/0.3) for integer xl (proven exact)
        int yi = (10 * (int)yl) / 3;
        if (xi < 0) xi += BEVN;
        if (yi < 0) yi += BEVN;

        int packed = ((int)n << 12) | (ui << 7) | vi;
        atomicMax(&win[bc * NCELL + xi * BEVN + yi], packed);
    }
}

// Emit from transposed features (channel-last, contiguous 320B per winner).
__global__ void emit_t_kernel(const float* __restrict__ featT,
                              const int* __restrict__ win,
                              float* __restrict__ out) {
    __shared__ int   sbase[NCAM][32];
    __shared__ float sacc[CFEAT][33];
    int b = blockIdx.y;
    int cell0 = blockIdx.x * 32;
    int t = threadIdx.x;

    if (t < 32 * NCAM) {
        int c = t >> 5, celli = t & 31;
        int cell = cell0 + celli;
        int base = -1;
        if (cell < NCELL) {
            int w = win[(b * NCAM + c) * NCELL + cell];
            if (w >= 0) {
                int ui = (w >> 7) & 31;
                int vi = w & 127;
                base = ((b * NCAM + c) * FHW + ui * FW + vi) * CFEAT;
            }
        }
        sbase[c][celli] = base;
    }
    __syncthreads();

    int celli = t >> 3;
    int sub   = t & 7;
    float acc[10];
#pragma unroll
    for (int k = 0; k < 10; ++k) acc[k] = 0.0f;
    for (int c = 0; c < NCAM; ++c) {
        int base = sbase[c][celli];
        if (base >= 0) {
#pragma unroll
            for (int k = 0; k < 10; ++k)
                acc[k] += featT[base + sub * 10 + k];
        }
    }
#pragma unroll
    for (int k = 0; k < 10; ++k) sacc[sub * 10 + k][celli] = acc[k];
    __syncthreads();

    for (int w = t; w < 32 * CFEAT; w += 256) {
        int ch = w >> 5, ci = w & 31;
        int cell = cell0 + ci;
        if (cell < NCELL)
            out[(b * CFEAT + ch) * NCELL + cell] = sacc[ch][ci];
    }
}

// ---------- fallback (round-2 path) if ws too small for lists ----------
__global__ void transpose_prep_kernel(const float* __restrict__ feat,
                                      float* __restrict__ featT,
                                      const float* __restrict__ l2i,
                                      const float* __restrict__ iam,
                                      const float* __restrict__ lam,
                                      double* __restrict__ W,
                                      int* __restrict__ win) {
    __shared__ float tile[CFEAT * 65];
    int bx = blockIdx.x;
    int t  = threadIdx.x;
    { int i = bx * 256 + t; if (i < NWIN) win[i] = -1; }  // needs >=1519 blocks? no: TBLK=528*256=135168 < NWIN -> grid-stride
    for (int i = bx * 256 + t + TBLK*256; i < NWIN; i += TBLK*256) win[i] = -1;
    if (bx == 0 && t < 64) prep_full(t, l2i, iam, lam, W);
    int bc = bx / 44;
    int s0 = (bx % 44) * 64;
    int j   = t & 63;
    int ch0 = t >> 6;
    for (int ch = ch0; ch < CFEAT; ch += 4)
        tile[ch * 65 + j] = feat[(bc * CFEAT + ch) * FHW + s0 + j];
    __syncthreads();
    for (int w = t; w < 64 * CFEAT; w += 256) {
        int jj = w / CFEAT, ch = w % CFEAT;
        featT[((size_t)bc * FHW + s0 + jj) * CFEAT + ch] = tile[ch * 65 + jj];
    }
}

__global__ void project_direct_kernel(const float* __restrict__ pts,
                                      const double* __restrict__ W,
                                      int* __restrict__ win) {
    int n  = blockIdx.x * blockDim.x + threadIdx.x;
    if (n >= NPTS) return;
    int bc = blockIdx.y;
    int b  = bc / NCAM;
    const double* IL = W + b * 12;
    const double* K  = W + OFF_CAM + bc * 32;

    float4 p = ((const float4*)pts)[b * NPTS + n];
    double pm0 = (double)p.x - IL[9];
    double pm1 = (double)p.y - IL[10];
    double pm2 = (double)p.z - IL[11];
    double cv0 = IL[0]*pm0 + IL[1]*pm1 + IL[2]*pm2;
    double cv1 = IL[3]*pm0 + IL[4]*pm1 + IL[5]*pm2;
    double cv2 = IL[6]*pm0 + IL[7]*pm1 + IL[8]*pm2;
    double zc = K[0]*cv0 + K[1]*cv1 + K[2]*cv2 + K[3];
    double d  = fmin(fmax(zc, 1e-5), 1e5);
    double inv_d = 1.0 / d;
    double n0 = K[4]*cv0 + K[5]*cv1 + K[6]*cv2 + K[7];
    double n1 = K[8]*cv0 + K[9]*cv1 + K[10]*cv2 + K[11];
    double c1 = n0 * inv_d + (K[12]*d + K[13]);
    double c0 = n1 * inv_d + (K[14]*d + K[15]);
    if (!((c0 >= 0.0) && (c0 < 256.0) && (c1 >= 0.0) && (c1 < 704.0))) return;
    double dd = d * d;
    double X = K[16]*n1 + K[17]*n0 + K[18]*dd + K[19]*d + K[20];
    double Y = K[21]*n1 + K[22]*n0 + K[23]*dd + K[24]*d + K[25];
    double Z = K[26]*n1 + K[27]*n0 + K[28]*dd + K[29]*d + K[30];
    double xl = trunc(X);
    double yl = trunc(Y);
    if (!((Z >= 0.0) && (xl >= -54.0) && (yl >= -54.0) && (xl < 54.0) && (yl < 54.0)))
        return;
    int ui = (int)(c0 * 0.125);
    int vi = (int)(c1 * 0.125);
    int xi = (10 * (int)xl) / 3;
    int yi = (10 * (int)yl) / 3;
    if (xi < 0) xi += BEVN;
    if (yi < 0) yi += BEVN;
    int packed = (n << 12) | (ui << 7) | vi;
    atomicMax(&win[bc * NCELL + xi * BEVN + yi], packed);
}

extern "C" void kernel_launch(void* const* d_in, const int* in_sizes, int n_in,
                              void* d_out, int out_size, void* d_ws, size_t ws_size,
                              hipStream_t stream) {
    const float* img_feat = (const float*)d_in[0];
    const float* points   = (const float*)d_in[1];
    const float* l2i      = (const float*)d_in[2];
    const float* iam      = (const float*)d_in[3];
    const float* lam      = (const float*)d_in[4];

    double*       W     = (double*)d_ws;
    int*          win   = (int*)((char*)d_ws + WIN_BYTE_OFF);
    float*        featT = (float*)((char*)d_ws + FEATT_OFF);
    unsigned int* list  = (unsigned int*)((char*)d_ws + LIST_OFF);
    int*          cnt   = (int*)((char*)d_ws + CNT_OFF);

    if (ws_size >= WS_NEED) {
        hipLaunchKernelGGL(fusedA_kernel, dim3(GRID_A), dim3(256), 0, stream,
                           img_feat, featT, points, l2i, iam, lam, W, win, list, cnt);
        hipLaunchKernelGGL(proj2_kernel, dim3(NREG, NB * NCAM), dim3(64), 0, stream,
                           points, W, list, cnt, win);
        hipLaunchKernelGGL(emit_t_kernel, dim3((NCELL + 31) / 32, NB), dim3(256), 0,
                           stream, featT, win, (float*)d_out);
    } else {
        // fallback: direct per-(b,c,n) projection (round-2 structure)
        hipLaunchKernelGGL(transpose_prep_kernel, dim3(TBLK), dim3(256), 0, stream,
                           img_feat, featT, l2i, iam, lam, W, win);
        hipLaunchKernelGGL(project_direct_kernel, dim3((NPTS + 255) / 256, NB * NCAM),
                           dim3(256), 0, stream, points, W, win);
        hipLaunchKernelGGL(emit_t_kernel, dim3((NCELL + 31) / 32, NB), dim3(256), 0,
                           stream, featT, win, (float*)d_out);
    }
}

// Round 4
// 52.811 us; speedup vs baseline: 1.3803x; 1.0997x over previous
//
#include <hip/hip_runtime.h>

#define NB    2
#define NCAM  6
#define CFEAT 80
#define FH    32
#define FW    88
#define FHW   (FH*FW)          // 2816
#define NPTS  150000
#define BEVN  180
#define NCELL (BEVN*BEVN)      // 32400
#define NWIN  (NB*NCAM*NCELL)  // 388800

#define NREG  586              // ceil(NPTS/256)
#define PBLK  (NB*NREG)        // 1172 project blocks
#define TBLK  (NB*NCAM*44)     // 528 transpose blocks (FHW = 44*64)
#define GRID_PT (PBLK + TBLK)  // 1700

// ---- ws layout ----
#define WIN_BYTE_OFF 4096
#define WIN_BYTES   (NWIN*4)                          // 1,555,200
#define FEATT_OFF   ((size_t)(WIN_BYTE_OFF + WIN_BYTES + 255) & ~(size_t)255)
#define FEATT_BYTES ((size_t)NB*NCAM*FHW*CFEAT*4)     // 10,813,440
#define WS_NEED     (FEATT_OFF + FEATT_BYTES)

__device__ inline void inv3x3(const double m[9], double* o) {
    double c00 = m[4]*m[8] - m[5]*m[7];
    double c01 = m[5]*m[6] - m[3]*m[8];
    double c02 = m[3]*m[7] - m[4]*m[6];
    double det = m[0]*c00 + m[1]*c01 + m[2]*c02;
    double id  = 1.0 / det;
    o[0] = c00 * id;
    o[1] = (m[2]*m[7] - m[1]*m[8]) * id;
    o[2] = (m[1]*m[5] - m[2]*m[4]) * id;
    o[3] = c01 * id;
    o[4] = (m[0]*m[8] - m[2]*m[6]) * id;
    o[5] = (m[2]*m[3] - m[0]*m[5]) * id;
    o[6] = c02 * id;
    o[7] = (m[1]*m[6] - m[0]*m[7]) * id;
    o[8] = (m[0]*m[4] - m[1]*m[3]) * id;
}

__device__ inline void inv3x3f(const float m[9], float* o) {
    float c00 = m[4]*m[8] - m[5]*m[7];
    float c01 = m[5]*m[6] - m[3]*m[8];
    float c02 = m[3]*m[7] - m[4]*m[6];
    float det = m[0]*c00 + m[1]*c01 + m[2]*c02;
    float id  = 1.0f / det;
    o[0] = c00 * id;
    o[1] = (m[2]*m[7] - m[1]*m[8]) * id;
    o[2] = (m[1]*m[5] - m[2]*m[4]) * id;
    o[3] = c01 * id;
    o[4] = (m[0]*m[8] - m[2]*m[6]) * id;
    o[5] = (m[2]*m[3] - m[0]*m[5]) * id;
    o[6] = c02 * id;
    o[7] = (m[1]*m[6] - m[0]*m[7]) * id;
    o[8] = (m[0]*m[4] - m[1]*m[3]) * id;
}

// Conservative f32 frustum filter (identical to round-3, proven non-dropping):
// margins cover worst-case f32 cancellation (~0.03) with 20x floor.
__device__ inline bool filt(float cv0, float cv1, float cv2, const float* C) {
    float zc = C[0]*cv0 + C[1]*cv1 + C[2]*cv2 + C[3];
    float n0 = C[4]*cv0 + C[5]*cv1 + C[6]*cv2 + C[7];
    float n1 = C[8]*cv0 + C[9]*cv1 + C[10]*cv2 + C[11];
    if (zc >= 1e-3f) {
        float w0 = n0 + (C[12]*zc + C[13]) * zc;
        float w1 = n1 + (C[14]*zc + C[15]) * zc;
        float m0 = 0.5f + 2e-4f * (fabsf(w0) + 704.0f * zc);
        float m1 = 0.5f + 2e-4f * (fabsf(w1) + 256.0f * zc);
        return (w0 > -m0) && (w0 < 704.0f*zc + m0) && (w1 > -m1) && (w1 < 256.0f*zc + m1);
    }
    return (fabsf(n0) < 2.0f) && (fabsf(n1) < 2.0f);
}

// Per-block prep into LDS: f32 filter constants (t==0), f64 invLam (t==1),
// f64 folded per-cam coefficients (t==2..7). Bit-identical across blocks.
__device__ void prep_block(int t, int b,
                           const float* __restrict__ l2i,
                           const float* __restrict__ iam,
                           const float* __restrict__ lam,
                           double* __restrict__ sW,    // [0..11] IL, 12+c*33 cams
                           float* __restrict__ sFC,    // 6*16
                           float* __restrict__ sIL) {  // 12
    if (t == 0) {
        const float* Lb = lam + b * 16;
        float m[9];
        for (int i = 0; i < 3; ++i)
            for (int j = 0; j < 3; ++j) m[i*3+j] = Lb[i*4+j];
        inv3x3f(m, sIL);
        for (int i = 0; i < 3; ++i) sIL[9+i] = Lb[i*4+3];
        for (int c = 0; c < NCAM; ++c) {
            const float* L = l2i + (b*NCAM + c) * 16;
            const float* A = iam + (b*NCAM + c) * 16;
            float* C = sFC + c * 16;
            C[0]=L[8]; C[1]=L[9]; C[2]=L[10]; C[3]=L[11];
            for (int j = 0; j < 4; ++j) {
                C[4+j] = A[0]*L[j] + A[1]*L[4+j];
                C[8+j] = A[4]*L[j] + A[5]*L[4+j];
            }
            C[12]=A[2]; C[13]=A[3]; C[14]=A[6]; C[15]=A[7];
        }
    }
    if (t == 1) {
        const float* Lb = lam + b * 16;
        double m[9];
        for (int i = 0; i < 3; ++i)
            for (int j = 0; j < 3; ++j) m[i*3+j] = (double)Lb[i*4+j];
        inv3x3(m, sW);
        for (int i = 0; i < 3; ++i) sW[9+i] = (double)Lb[i*4+3];
    }
    if (t >= 2 && t < 2 + NCAM) {
        int c = t - 2;
        const float* L = l2i + (b*NCAM + c) * 16;
        const float* A = iam + (b*NCAM + c) * 16;
        double* K = sW + 12 + c * 33;
        K[0]=(double)L[8]; K[1]=(double)L[9]; K[2]=(double)L[10]; K[3]=(double)L[11];
        for (int j = 0; j < 4; ++j) {
            K[4+j] = (double)A[0]*(double)L[j] + (double)A[1]*(double)L[4+j];
            K[8+j] = (double)A[4]*(double)L[j] + (double)A[5]*(double)L[4+j];
        }
        K[12]=(double)A[2]; K[13]=(double)A[3]; K[14]=(double)A[6]; K[15]=(double)A[7];
        // scale_intrinsics bug replication (cam0 rows 0,2 /8; cam1 rows 1,2 /64)
        double ms[9], ts[3];
        for (int i = 0; i < 3; ++i) {
            double s = 1.0;
            if (c == 0 && (i == 0 || i == 2)) s = 0.125;
            if (c == 1 && (i == 1 || i == 2)) s = 0.015625;
            for (int j = 0; j < 3; ++j) ms[i*3+j] = (double)L[i*4+j] * s;
            ts[i] = (double)L[i*4+3] * s;
        }
        double IM[9];
        inv3x3(ms, IM);
        for (int rw = 0; rw < 3; ++rw) {
            double P0 = IM[rw*3+0] * 0.125;
            double P1 = IM[rw*3+1] * 0.125;
            double I2 = IM[rw*3+2];
            K[16 + rw*5 + 0] = P0;
            K[16 + rw*5 + 1] = P1;
            K[16 + rw*5 + 2] = P0*(double)A[6] + P1*(double)A[2];
            K[16 + rw*5 + 3] = P0*(double)A[7] + P1*(double)A[3] + I2;
            K[16 + rw*5 + 4] = -(IM[rw*3+0]*ts[0] + IM[rw*3+1]*ts[1] + IM[rw*3+2]*ts[2]);
        }
    }
}

// Fused: blocks [0,PBLK) = self-contained filter+project per (b, region);
//        blocks [PBLK,GRID_PT) = feature transpose (b,c,ch,hw)->(b,c,hw,ch).
__global__ void __launch_bounds__(256) pt_kernel(const float* __restrict__ pts,
                                                 const float* __restrict__ feat,
                                                 float* __restrict__ featT,
                                                 const float* __restrict__ l2i,
                                                 const float* __restrict__ iam,
                                                 const float* __restrict__ lam,
                                                 int* __restrict__ win) {
    __shared__ double smem[2600];   // 20800 B, aliased per block role
    int bx = blockIdx.x, t = threadIdx.x;

    if (bx >= PBLK) {
        // ---- transpose (round-3 verbatim) ----
        float* tile = (float*)smem;          // 80*65 floats
        int i  = bx - PBLK;
        int bc = i / 44;
        int s0 = (i % 44) * 64;
        int j   = t & 63;
        int ch0 = t >> 6;
        for (int ch = ch0; ch < CFEAT; ch += 4)
            tile[ch * 65 + j] = feat[(bc * CFEAT + ch) * FHW + s0 + j];
        __syncthreads();
        for (int w = t; w < 64 * CFEAT; w += 256) {
            int jj = w / CFEAT, ch = w % CFEAT;
            featT[((size_t)bc * FHW + s0 + jj) * CFEAT + ch] = tile[ch * 65 + jj];
        }
        return;
    }

    // ---- filter + project, fully in-block ----
    double*         sW    = smem;                       // 210 dbl
    float4*         sP    = (float4*)(smem + 210);      // 256 float4 (16B aligned)
    float*          sFC   = (float*)(sP + 256);         // 96 f
    float*          sIL   = sFC + 96;                   // 12 f
    int*            sCnt  = (int*)(sIL + 12);           // 24
    int*            sOff  = sCnt + 24;                  // 24
    int*            sT    = sOff + 24;                  // 1
    unsigned short* sList = (unsigned short*)(sT + 1);  // 1536

    int b = bx / NREG;
    int r = bx - b * NREG;
    int n = r * 256 + t;
    bool ok = (n < NPTS);
    float4 p = make_float4(0.f, 0.f, 0.f, 0.f);
    if (ok) p = ((const float4*)pts)[b * NPTS + n];
    sP[t] = p;
    prep_block(t, b, l2i, iam, lam, sW, sFC, sIL);
    __syncthreads();

    float pm0 = p.x - sIL[9], pm1 = p.y - sIL[10], pm2 = p.z - sIL[11];
    float cv0 = sIL[0]*pm0 + sIL[1]*pm1 + sIL[2]*pm2;
    float cv1 = sIL[3]*pm0 + sIL[4]*pm1 + sIL[5]*pm2;
    float cv2 = sIL[6]*pm0 + sIL[7]*pm1 + sIL[8]*pm2;

    int lane = t & 63, wid = t >> 6;
    unsigned long long bm[NCAM];
#pragma unroll
    for (int c = 0; c < NCAM; ++c) {
        bool pass = ok && filt(cv0, cv1, cv2, sFC + c * 16);
        bm[c] = __ballot(pass);
        if (lane == 0) sCnt[c*4 + wid] = __popcll(bm[c]);
    }
    __syncthreads();
    if (t == 0) {
        int acc = 0;
        for (int c = 0; c < NCAM; ++c)
            for (int w = 0; w < 4; ++w) { sOff[c*4 + w] = acc; acc += sCnt[c*4 + w]; }
        sT[0] = acc;
    }
    __syncthreads();
#pragma unroll
    for (int c = 0; c < NCAM; ++c) {
        if ((bm[c] >> lane) & 1ull) {
            int pos = sOff[c*4 + wid] + __popcll(bm[c] & ((1ull << lane) - 1ull));
            sList[pos] = (unsigned short)((c << 8) | t);
        }
    }
    __syncthreads();

    int T = sT[0];
    for (int e = t; e < T; e += 256) {
        int entry = sList[e];
        int px = entry & 255;
        int c  = entry >> 8;
        float4 q = sP[px];
        const double* IL = sW;
        const double* K  = sW + 12 + c * 33;

        double dm0 = (double)q.x - IL[9];
        double dm1 = (double)q.y - IL[10];
        double dm2 = (double)q.z - IL[11];
        double dv0 = IL[0]*dm0 + IL[1]*dm1 + IL[2]*dm2;
        double dv1 = IL[3]*dm0 + IL[4]*dm1 + IL[5]*dm2;
        double dv2 = IL[6]*dm0 + IL[7]*dm1 + IL[8]*dm2;

        double zc = K[0]*dv0 + K[1]*dv1 + K[2]*dv2 + K[3];
        double d  = fmin(fmax(zc, 1e-5), 1e5);
        double inv_d = 1.0 / d;
        double n0 = K[4]*dv0 + K[5]*dv1 + K[6]*dv2 + K[7];
        double n1 = K[8]*dv0 + K[9]*dv1 + K[10]*dv2 + K[11];
        double c1 = n0 * inv_d + (K[12]*d + K[13]);   // col, [0,704)
        double c0 = n1 * inv_d + (K[14]*d + K[15]);   // row, [0,256)
        if (!((c0 >= 0.0) && (c0 < 256.0) && (c1 >= 0.0) && (c1 < 704.0))) continue;

        double dd = d * d;
        double X = K[16]*n1 + K[17]*n0 + K[18]*dd + K[19]*d + K[20];
        double Y = K[21]*n1 + K[22]*n0 + K[23]*dd + K[24]*d + K[25];
        double Z = K[26]*n1 + K[27]*n0 + K[28]*dd + K[29]*d + K[30];
        double xl = trunc(X);
        double yl = trunc(Y);
        if (!((Z >= 0.0) && (xl >= -54.0) && (yl >= -54.0) && (xl < 54.0) && (yl < 54.0)))
            continue;

        int ui = (int)(c0 * 0.125);
        int vi = (int)(c1 * 0.125);
        int xi = (10 * (int)xl) / 3;   // == trunc(xl/0.3) for integer xl (exact)
        int yi = (10 * (int)yl) / 3;
        if (xi < 0) xi += BEVN;
        if (yi < 0) yi += BEVN;

        int nn = r * 256 + px;
        int packed = (nn << 12) | (ui << 7) | vi;
        atomicMax(&win[(b*NCAM + c) * NCELL + xi * BEVN + yi], packed);
    }
}

// Emit from transposed features (round-3 verbatim, known-good).
__global__ void emit_t_kernel(const float* __restrict__ featT,
                              const int* __restrict__ win,
                              float* __restrict__ out) {
    __shared__ int   sbase[NCAM][32];
    __shared__ float sacc[CFEAT][33];
    int b = blockIdx.y;
    int cell0 = blockIdx.x * 32;
    int t = threadIdx.x;

    if (t < 32 * NCAM) {
        int c = t >> 5, celli = t & 31;
        int cell = cell0 + celli;
        int base = -1;
        if (cell < NCELL) {
            int w = win[(b * NCAM + c) * NCELL + cell];
            if (w >= 0) {
                int ui = (w >> 7) & 31;
                int vi = w & 127;
                base = ((b * NCAM + c) * FHW + ui * FW + vi) * CFEAT;
            }
        }
        sbase[c][celli] = base;
    }
    __syncthreads();

    int celli = t >> 3;
    int sub   = t & 7;
    float acc[10];
#pragma unroll
    for (int k = 0; k < 10; ++k) acc[k] = 0.0f;
    for (int c = 0; c < NCAM; ++c) {
        int base = sbase[c][celli];
        if (base >= 0) {
#pragma unroll
            for (int k = 0; k < 10; ++k)
                acc[k] += featT[base + sub * 10 + k];
        }
    }
#pragma unroll
    for (int k = 0; k < 10; ++k) sacc[sub * 10 + k][celli] = acc[k];
    __syncthreads();

    for (int w = t; w < 32 * CFEAT; w += 256) {
        int ch = w >> 5, ci = w & 31;
        int cell = cell0 + ci;
        if (cell < NCELL)
            out[(b * CFEAT + ch) * NCELL + cell] = sacc[ch][ci];
    }
}

// Fallback emit from original layout (only if ws can't hold featT).
__global__ void emit_kernel(const float* __restrict__ feat,
                            const int* __restrict__ win,
                            float* __restrict__ out) {
    __shared__ int   sbase[32][NCAM];
    __shared__ float sacc[32][81];
    int b = blockIdx.y;
    int cell0 = blockIdx.x * 32;
    int t = threadIdx.x;

    if (t < 32 * NCAM) {
        int celli = t / NCAM, c = t % NCAM;
        int cell = cell0 + celli;
        int base = -1;
        if (cell < NCELL) {
            int w = win[(b * NCAM + c) * NCELL + cell];
            if (w >= 0) {
                int ui = (w >> 7) & 31;
                int vi = w & 127;
                base = ((b * NCAM + c) * CFEAT) * FHW + ui * FW + vi;
            }
        }
        sbase[celli][c] = base;
    }
    __syncthreads();

    int celli = t & 31;
    int sub   = t >> 5;
    for (int k = 0; k < 10; ++k) {
        int ch = sub * 10 + k;
        float acc = 0.0f;
        for (int c = 0; c < NCAM; ++c) {
            int base = sbase[celli][c];
            if (base >= 0) acc += feat[base + ch * FHW];
        }
        sacc[celli][ch] = acc;
    }
    __syncthreads();

    for (int w = t; w < 32 * CFEAT; w += 256) {
        int ch = w >> 5, ci = w & 31;
        int cell = cell0 + ci;
        if (cell < NCELL)
            out[(b * CFEAT + ch) * NCELL + cell] = sacc[ci][ch];
    }
}

extern "C" void kernel_launch(void* const* d_in, const int* in_sizes, int n_in,
                              void* d_out, int out_size, void* d_ws, size_t ws_size,
                              hipStream_t stream) {
    const float* img_feat = (const float*)d_in[0];
    const float* points   = (const float*)d_in[1];
    const float* l2i      = (const float*)d_in[2];
    const float* iam      = (const float*)d_in[3];
    const float* lam      = (const float*)d_in[4];

    int*   win   = (int*)((char*)d_ws + WIN_BYTE_OFF);
    float* featT = (float*)((char*)d_ws + FEATT_OFF);
    bool use_t = ws_size >= WS_NEED;

    hipMemsetAsync(win, 0xFF, WIN_BYTES, stream);   // all cells -> -1

    hipLaunchKernelGGL(pt_kernel, dim3(use_t ? GRID_PT : PBLK), dim3(256), 0, stream,
                       points, img_feat, featT, l2i, iam, lam, win);

    if (use_t) {
        hipLaunchKernelGGL(emit_t_kernel, dim3((NCELL + 31) / 32, NB), dim3(256), 0,
                           stream, featT, win, (float*)d_out);
    } else {
        hipLaunchKernelGGL(emit_kernel, dim3((NCELL + 31) / 32, NB), dim3(256), 0,
                           stream, img_feat, win, (float*)d_out);
    }
}